// Round 6
// baseline (2894.533 us; speedup 1.0000x reference)
//
#include <hip/hip_runtime.h>
#include <hip/hip_cooperative_groups.h>
#include <math.h>

namespace cg = cooperative_groups;

#define H_IMG 768
#define W_IMG 1024
#define NPTS (H_IMG * W_IMG)
#define NITER 10
#define NTHR 256
#define DIST_THR (100.0f / 15.0f)
#define NORMAL_THR 0.34f

struct SharedScratch {
    float  smemF[4][29];
    double smemD[4][29];
    float  pose[12];
};

// ---------------------------------------------------------------- prep: backproject + np.gradient normals
template<int PPTL, int TOTT>
__device__ __forceinline__ void dev_prep(int tid, const float* __restrict__ depth,
                                         const float* __restrict__ K,
                                         float* __restrict__ ref_grid,
                                         float* __restrict__ ref_nrm) {
    float Ki[9];
    {
        double a = K[0], b = K[1], cc = K[2];
        double d = K[3], e = K[4], f = K[5];
        double g = K[6], h = K[7], i = K[8];
        double det = a * (e * i - f * h) - b * (d * i - f * g) + cc * (d * h - e * g);
        double idet = 1.0 / det;
        Ki[0] = (float)((e * i - f * h) * idet);
        Ki[1] = (float)((cc * h - b * i) * idet);
        Ki[2] = (float)((b * f - cc * e) * idet);
        Ki[3] = (float)((f * g - d * i) * idet);
        Ki[4] = (float)((a * i - cc * g) * idet);
        Ki[5] = (float)((cc * d - a * f) * idet);
        Ki[6] = (float)((d * h - e * g) * idet);
        Ki[7] = (float)((b * g - a * h) * idet);
        Ki[8] = (float)((a * e - b * d) * idet);
    }
#pragma unroll
    for (int q = 0; q < PPTL; ++q) {
        int p = tid + q * TOTT;
        int v = p >> 10, u = p & 1023;
        float uf = (float)u, vf = (float)v;
        float d0 = depth[p];
        ref_grid[3 * p + 0] = (Ki[0] * uf + Ki[1] * vf + Ki[2]) * d0;
        ref_grid[3 * p + 1] = (Ki[3] * uf + Ki[4] * vf + Ki[5]) * d0;
        ref_grid[3 * p + 2] = (Ki[6] * uf + Ki[7] * vf + Ki[8]) * d0;
        int um = u > 0 ? u - 1 : 0, up = u < W_IMG - 1 ? u + 1 : W_IMG - 1;
        int vm = v > 0 ? v - 1 : 0, vp = v < H_IMG - 1 ? v + 1 : H_IMG - 1;
        float su = (u > 0 && u < W_IMG - 1) ? 0.5f : 1.0f;
        float sv = (v > 0 && v < H_IMG - 1) ? 0.5f : 1.0f;
        float dl = depth[v * W_IMG + um], dr = depth[v * W_IMG + up];
        float dt = depth[vm * W_IMG + u], db = depth[vp * W_IMG + u];
        float umf = (float)um, upf = (float)up, vmf = (float)vm, vpf = (float)vp;
        float lx = (Ki[0] * umf + Ki[1] * vf + Ki[2]) * dl;
        float ly = (Ki[3] * umf + Ki[4] * vf + Ki[5]) * dl;
        float lz = (Ki[6] * umf + Ki[7] * vf + Ki[8]) * dl;
        float rx = (Ki[0] * upf + Ki[1] * vf + Ki[2]) * dr;
        float ry = (Ki[3] * upf + Ki[4] * vf + Ki[5]) * dr;
        float rz = (Ki[6] * upf + Ki[7] * vf + Ki[8]) * dr;
        float tx = (Ki[0] * uf + Ki[1] * vmf + Ki[2]) * dt;
        float ty = (Ki[3] * uf + Ki[4] * vmf + Ki[5]) * dt;
        float tz = (Ki[6] * uf + Ki[7] * vmf + Ki[8]) * dt;
        float bx = (Ki[0] * uf + Ki[1] * vpf + Ki[2]) * db;
        float by = (Ki[3] * uf + Ki[4] * vpf + Ki[5]) * db;
        float bz = (Ki[6] * uf + Ki[7] * vpf + Ki[8]) * db;
        float dux = (rx - lx) * su, duy = (ry - ly) * su, duz = (rz - lz) * su;
        float dvx = (bx - tx) * sv, dvy = (by - ty) * sv, dvz = (bz - tz) * sv;
        float nx = duy * dvz - duz * dvy;
        float ny = duz * dvx - dux * dvz;
        float nz = dux * dvy - duy * dvx;
        float il = 1.0f / sqrtf(nx * nx + ny * ny + nz * nz + 1e-12f);
        ref_nrm[3 * p + 0] = nx * il;
        ref_nrm[3 * p + 1] = ny * il;
        ref_nrm[3 * p + 2] = nz * il;
    }
}

template<int PPTL, int TOTT>
__device__ __forceinline__ void dev_load_pn(int tid, const float* __restrict__ tp,
                                            const float* __restrict__ tn,
                                            float (*p)[3], float (*n)[3]) {
#pragma unroll
    for (int q = 0; q < PPTL; ++q) {
        int i = tid + q * TOTT;
        p[q][0] = tp[3 * i + 0]; p[q][1] = tp[3 * i + 1]; p[q][2] = tp[3 * i + 2];
        n[q][0] = tn[3 * i + 0]; n[q][1] = tn[3 * i + 1]; n[q][2] = tn[3 * i + 2];
    }
}

// ---------------------------------------------------------------- sweep: residuals + block reduce -> partials (col-major [29][NB])
template<int PPTL, int NB>
__device__ __forceinline__ void dev_sweep(const float (*p)[3], const float (*n)[3],
                                          const float* __restrict__ grid,
                                          const float* __restrict__ nrm,
                                          const float* __restrict__ K,
                                          float* __restrict__ partials,
                                          SharedScratch* sh) {
    const float R0 = sh->pose[0], R1 = sh->pose[1], R2 = sh->pose[2];
    const float R3 = sh->pose[3], R4 = sh->pose[4], R5 = sh->pose[5];
    const float R6 = sh->pose[6], R7 = sh->pose[7], R8 = sh->pose[8];
    const float t0 = sh->pose[9], t1 = sh->pose[10], t2 = sh->pose[11];
    const float K0 = K[0], K1 = K[1], K2 = K[2];
    const float K3 = K[3], K4 = K[4], K5 = K[5];
    const float K6 = K[6], K7 = K[7], K8 = K[8];

    float acc[29];
#pragma unroll
    for (int k = 0; k < 29; ++k) acc[k] = 0.f;

#pragma unroll
    for (int q = 0; q < PPTL; ++q) {
        float p0 = p[q][0], p1 = p[q][1], p2 = p[q][2];
        float n0 = n[q][0], n1 = n[q][1], n2 = n[q][2];
        float d0 = p0 - t0, d1 = p1 - t1, d2 = p2 - t2;
        float pc0 = R0 * d0 + R3 * d1 + R6 * d2;
        float pc1 = R1 * d0 + R4 * d1 + R7 * d2;
        float pc2 = R2 * d0 + R5 * d1 + R8 * d2;
        float nc0 = R0 * n0 + R3 * n1 + R6 * n2;
        float nc1 = R1 * n0 + R4 * n1 + R7 * n2;
        float nc2 = R2 * n0 + R5 * n1 + R8 * n2;
        float uu = K0 * pc0 + K1 * pc1 + K2 * pc2;
        float vv = K3 * pc0 + K4 * pc1 + K5 * pc2;
        float zz = K6 * pc0 + K7 * pc1 + K8 * pc2;
        float zs = (fabsf(zz) > 1e-8f) ? zz : 1e-8f;
        float uf = uu / zs, vf = vv / zs;
        bool valid = (uf > 0.f) && (uf < (float)W_IMG) && (vf > 0.f) && (vf < (float)H_IMG) && (zz > 1e-6f);
        int iu = (int)fminf(fmaxf(uf, 0.f), (float)(W_IMG - 1));
        int iv = (int)fminf(fmaxf(vf, 0.f), (float)(H_IMG - 1));
        int gi = ((iv << 10) + iu) * 3;
        float rg0 = grid[gi + 0], rg1 = grid[gi + 1], rg2 = grid[gi + 2];
        float rn0 = nrm[gi + 0], rn1 = nrm[gi + 1], rn2 = nrm[gi + 2];
        float dd0 = rg0 - pc0, dd1 = rg1 - pc1, dd2 = rg2 - pc2;
        float dist = sqrtf(dd0 * dd0 + dd1 * dd1 + dd2 * dd2 + 1e-12f);
        valid = valid && (dist < DIST_THR) && (rn0 * nc0 + rn1 * nc1 + rn2 * nc2 > NORMAL_THR);
        if (valid) {
            float rw0 = R0 * rg0 + R1 * rg1 + R2 * rg2 + t0;
            float rw1 = R3 * rg0 + R4 * rg1 + R5 * rg2 + t1;
            float rw2 = R6 * rg0 + R7 * rg1 + R8 * rg2 + t2;
            float r = n0 * (rw0 - p0) + n1 * (rw1 - p1) + n2 * (rw2 - p2);
            float J[6];
            J[0] = rw1 * n2 - rw2 * n1;
            J[1] = rw2 * n0 - rw0 * n2;
            J[2] = rw0 * n1 - rw1 * n0;
            J[3] = n0; J[4] = n1; J[5] = n2;
            int cI = 0;
#pragma unroll
            for (int a = 0; a < 6; ++a)
#pragma unroll
                for (int b = a; b < 6; ++b) acc[cI++] += J[a] * J[b];
#pragma unroll
            for (int a = 0; a < 6; ++a) acc[21 + a] += J[a] * r;
            acc[27] += r * r;
            acc[28] += 1.f;
        }
    }

#pragma unroll
    for (int k = 0; k < 29; ++k) {
#pragma unroll
        for (int off = 32; off > 0; off >>= 1) acc[k] += __shfl_down(acc[k], off);
    }
    int lane = threadIdx.x & 63, wv = threadIdx.x >> 6;
    if (lane == 0) {
#pragma unroll
        for (int k = 0; k < 29; ++k) sh->smemF[wv][k] = acc[k];
    }
    __syncthreads();
    if (threadIdx.x < 29) {
        // column-major: partials[k * NB + blockIdx.x]
        partials[threadIdx.x * NB + blockIdx.x] =
            sh->smemF[0][threadIdx.x] + sh->smemF[1][threadIdx.x] +
            sh->smemF[2][threadIdx.x] + sh->smemF[3][threadIdx.x];
    }
}

// ---------------------------------------------------------------- reduce partials + pivot-free 6x6 solve (single block)
template<int NB>
__device__ __forceinline__ void dev_reduce_solve(const float* __restrict__ partials,
                                                 double* x, SharedScratch* sh,
                                                 float* __restrict__ poseG,
                                                 float* __restrict__ out_final) {
    constexpr int ROWS = NB / NTHR;
    double a2[29];
#pragma unroll
    for (int k = 0; k < 29; ++k) {
        double s = 0.0;
#pragma unroll
        for (int j = 0; j < ROWS; ++j)
            s += (double)partials[k * NB + threadIdx.x + j * NTHR];   // coalesced
        a2[k] = s;
    }
#pragma unroll
    for (int k = 0; k < 29; ++k) {
#pragma unroll
        for (int off = 32; off > 0; off >>= 1) a2[k] += __shfl_down(a2[k], off);
    }
    int lane = threadIdx.x & 63, wv = threadIdx.x >> 6;
    if (lane == 0) {
#pragma unroll
        for (int k = 0; k < 29; ++k) sh->smemD[wv][k] = a2[k];
    }
    __syncthreads();
    if (threadIdx.x == 0) {
        double T[29];
#pragma unroll
        for (int k = 0; k < 29; ++k)
            T[k] = sh->smemD[0][k] + sh->smemD[1][k] + sh->smemD[2][k] + sh->smemD[3][k];
        double M[6][7];
        int cI = 0;
#pragma unroll
        for (int a = 0; a < 6; ++a)
#pragma unroll
            for (int b = a; b < 6; ++b) { M[a][b] = T[cI]; M[b][a] = T[cI]; ++cI; }
#pragma unroll
        for (int a = 0; a < 6; ++a) M[a][6] = T[21 + a];
        double cost = T[27] / fmax(T[28], 1.0);
#pragma unroll
        for (int d = 0; d < 6; ++d) M[d][d] += 1e-9;
#pragma unroll
        for (int col = 0; col < 6; ++col) {
            double ip = 1.0 / M[col][col];
#pragma unroll
            for (int r = col + 1; r < 6; ++r) {
                double f = M[r][col] * ip;
#pragma unroll
                for (int k = col; k < 7; ++k) M[r][k] -= f * M[col][k];
            }
        }
        double y[6];
#pragma unroll
        for (int i2 = 5; i2 >= 0; --i2) {
            double s = M[i2][6];
#pragma unroll
            for (int j = i2 + 1; j < 6; ++j) s -= M[i2][j] * y[j];
            y[i2] = s / M[i2][i2];
        }
#pragma unroll
        for (int k = 0; k < 6; ++k) x[k] -= y[k];
        double th2 = x[0] * x[0] + x[1] * x[1] + x[2] * x[2];
        double th = sqrt(th2 + 1e-12);
        double sA = sin(th) / th;
        double sB = (1.0 - cos(th)) / (th2 + 1e-12);
        double R[9];
        R[0] = 1.0 + sB * (-(x[1] * x[1] + x[2] * x[2]));
        R[1] = sA * (-x[2]) + sB * (x[0] * x[1]);
        R[2] = sA * ( x[1]) + sB * (x[0] * x[2]);
        R[3] = sA * ( x[2]) + sB * (x[0] * x[1]);
        R[4] = 1.0 + sB * (-(x[0] * x[0] + x[2] * x[2]));
        R[5] = sA * (-x[0]) + sB * (x[1] * x[2]);
        R[6] = sA * (-x[1]) + sB * (x[0] * x[2]);
        R[7] = sA * ( x[0]) + sB * (x[1] * x[2]);
        R[8] = 1.0 + sB * (-(x[0] * x[0] + x[1] * x[1]));
#pragma unroll
        for (int k = 0; k < 9; ++k) poseG[k] = (float)R[k];
        poseG[9] = (float)x[3]; poseG[10] = (float)x[4]; poseG[11] = (float)x[5];
        if (out_final) {
            out_final[0]  = (float)R[0]; out_final[1]  = (float)R[1]; out_final[2]  = (float)R[2]; out_final[3]  = (float)x[3];
            out_final[4]  = (float)R[3]; out_final[5]  = (float)R[4]; out_final[6]  = (float)R[5]; out_final[7]  = (float)x[4];
            out_final[8]  = (float)R[6]; out_final[9]  = (float)R[7]; out_final[10] = (float)R[8]; out_final[11] = (float)x[5];
            out_final[12] = 0.f; out_final[13] = 0.f; out_final[14] = 0.f; out_final[15] = 1.f;
            out_final[16] = (float)cost;
        }
    }
}

// ---------------------------------------------------------------- cooperative single-kernel path
template<int NB>
__global__ __launch_bounds__(NTHR, NB / 256) void icp_coop(
    const float* __restrict__ depth, const float* __restrict__ tp,
    const float* __restrict__ tn, const float* __restrict__ K,
    float* __restrict__ out, float* __restrict__ ref_grid,
    float* __restrict__ ref_nrm, float* __restrict__ partials,
    float* __restrict__ poseG) {
    constexpr int TOTT = NB * NTHR;
    constexpr int PPTL = NPTS / TOTT;
    __shared__ SharedScratch sh;
    cg::grid_group gg = cg::this_grid();
    const int tid = blockIdx.x * NTHR + threadIdx.x;

    dev_prep<PPTL, TOTT>(tid, depth, K, ref_grid, ref_nrm);

    // target points/normals live in registers for all 10 iterations
    float p[PPTL][3], n[PPTL][3];
    dev_load_pn<PPTL, TOTT>(tid, tp, tn, p, n);

    double x[6] = {0, 0, 0, 0, 0, 0};   // authoritative only on block 0 / thread 0
    gg.sync();                          // prep visible everywhere

    for (int it = 0; it < NITER; ++it) {
        if (threadIdx.x < 12) {
            sh.pose[threadIdx.x] = (it == 0)
                ? ((threadIdx.x == 0 || threadIdx.x == 4 || threadIdx.x == 8) ? 1.f : 0.f)
                : poseG[threadIdx.x];
        }
        __syncthreads();
        dev_sweep<PPTL, NB>(p, n, ref_grid, ref_nrm, K, partials, &sh);
        gg.sync();                      // partials complete
        if (blockIdx.x == 0)
            dev_reduce_solve<NB>(partials, x, &sh, poseG,
                                 (it == NITER - 1) ? out : nullptr);
        gg.sync();                      // pose visible
    }
}

// ---------------------------------------------------------------- fallback multi-dispatch path (NB = 256)
__global__ __launch_bounds__(NTHR) void k_prep_f(const float* __restrict__ depth,
                                                 const float* __restrict__ K,
                                                 float* __restrict__ ref_grid,
                                                 float* __restrict__ ref_nrm) {
    dev_prep<12, 65536>(blockIdx.x * NTHR + threadIdx.x, depth, K, ref_grid, ref_nrm);
}

__global__ __launch_bounds__(NTHR) void k_sweep_f(int it, const float* __restrict__ poseG,
                                                  const float* __restrict__ tp,
                                                  const float* __restrict__ tn,
                                                  const float* __restrict__ grid,
                                                  const float* __restrict__ nrm,
                                                  const float* __restrict__ K,
                                                  float* __restrict__ partials) {
    __shared__ SharedScratch sh;
    const int tid = blockIdx.x * NTHR + threadIdx.x;
    if (threadIdx.x < 12) {
        sh.pose[threadIdx.x] = (it == 0)
            ? ((threadIdx.x == 0 || threadIdx.x == 4 || threadIdx.x == 8) ? 1.f : 0.f)
            : poseG[threadIdx.x];
    }
    __syncthreads();
    float p[12][3], n[12][3];
    dev_load_pn<12, 65536>(tid, tp, tn, p, n);
    dev_sweep<12, 256>(p, n, grid, nrm, K, partials, &sh);
}

__global__ __launch_bounds__(NTHR) void k_solve_f(int it, const float* __restrict__ partials,
                                                  double* __restrict__ xbuf,
                                                  float* __restrict__ poseG,
                                                  float* __restrict__ out) {
    __shared__ SharedScratch sh;
    double x[6] = {0, 0, 0, 0, 0, 0};
    if (threadIdx.x == 0 && it > 0) {
#pragma unroll
        for (int k = 0; k < 6; ++k) x[k] = xbuf[k];
    }
    dev_reduce_solve<256>(partials, x, &sh, poseG, (it == NITER - 1) ? out : nullptr);
    if (threadIdx.x == 0) {
#pragma unroll
        for (int k = 0; k < 6; ++k) xbuf[k] = x[k];
    }
}

// ---------------------------------------------------------------- launch
extern "C" void kernel_launch(void* const* d_in, const int* in_sizes, int n_in,
                              void* d_out, int out_size, void* d_ws, size_t ws_size,
                              hipStream_t stream) {
    const float* ref_depth      = (const float*)d_in[0];
    const float* target_pts     = (const float*)d_in[1];
    const float* target_normals = (const float*)d_in[2];
    const float* K              = (const float*)d_in[3];
    float* out = (float*)d_out;
    char* ws = (char*)d_ws;

    const size_t grid_bytes = (size_t)NPTS * 3 * sizeof(float);          // 9,437,184
    float*  ref_grid = (float*)ws;
    float*  ref_nrm  = (float*)(ws + grid_bytes);
    float*  partials = (float*)(ws + 2 * grid_bytes);                    // 29*1024 floats max
    float*  poseG    = (float*)(ws + 2 * grid_bytes + 32 * 1024 * sizeof(float));
    double* xbuf     = (double*)(ws + 2 * grid_bytes + 32 * 1024 * sizeof(float) + 64);

    void* args[] = {
        (void*)&ref_depth, (void*)&target_pts, (void*)&target_normals, (void*)&K,
        (void*)&out, (void*)&ref_grid, (void*)&ref_nrm, (void*)&partials, (void*)&poseG
    };

    hipError_t err = hipLaunchCooperativeKernel((const void*)&icp_coop<1024>,
                                                dim3(1024), dim3(NTHR), args, 0, stream);
    if (err != hipSuccess)
        err = hipLaunchCooperativeKernel((const void*)&icp_coop<512>,
                                         dim3(512), dim3(NTHR), args, 0, stream);
    if (err != hipSuccess)
        err = hipLaunchCooperativeKernel((const void*)&icp_coop<256>,
                                         dim3(256), dim3(NTHR), args, 0, stream);
    if (err != hipSuccess) {
        // last-resort: multi-dispatch pipeline (kernel boundaries = device-wide sync)
        k_prep_f<<<256, NTHR, 0, stream>>>(ref_depth, K, ref_grid, ref_nrm);
        for (int it = 0; it < NITER; ++it) {
            k_sweep_f<<<256, NTHR, 0, stream>>>(it, poseG, target_pts, target_normals,
                                                ref_grid, ref_nrm, K, partials);
            k_solve_f<<<1, NTHR, 0, stream>>>(it, partials, xbuf, poseG, out);
        }
    }
}

// Round 7
// 2659.222 us; speedup vs baseline: 1.0885x; 1.0885x over previous
//
#include <hip/hip_runtime.h>
#include <hip/hip_cooperative_groups.h>
#include <math.h>

namespace cg = cooperative_groups;

#define H_IMG 768
#define W_IMG 1024
#define NPTS (H_IMG * W_IMG)
#define NITER 10
#define NTHR 256
#define DIST_THR (100.0f / 15.0f)
#define NORMAL_THR 0.34f

struct SharedScratch {
    float  smemF[4][29];
    float  pose[12];
    double Tsh[29];
};

__device__ __forceinline__ int ut_off(int a, int b) {   // upper-tri row-major, a<=b
    return a * 6 - (a * (a - 1)) / 2 + (b - a);
}

// ---------------------------------------------------------------- prep: backproject + np.gradient normals
template<int PPTL, int TOTT, bool PACKED>
__device__ __forceinline__ void dev_prep(int tid, const float* __restrict__ depth,
                                         const float* __restrict__ K,
                                         float* __restrict__ refP,
                                         float* __restrict__ refG,
                                         float* __restrict__ refN) {
    float Ki[9];
    {
        double a = K[0], b = K[1], cc = K[2];
        double d = K[3], e = K[4], f = K[5];
        double g = K[6], h = K[7], i = K[8];
        double det = a * (e * i - f * h) - b * (d * i - f * g) + cc * (d * h - e * g);
        double idet = 1.0 / det;
        Ki[0] = (float)((e * i - f * h) * idet);
        Ki[1] = (float)((cc * h - b * i) * idet);
        Ki[2] = (float)((b * f - cc * e) * idet);
        Ki[3] = (float)((f * g - d * i) * idet);
        Ki[4] = (float)((a * i - cc * g) * idet);
        Ki[5] = (float)((cc * d - a * f) * idet);
        Ki[6] = (float)((d * h - e * g) * idet);
        Ki[7] = (float)((b * g - a * h) * idet);
        Ki[8] = (float)((a * e - b * d) * idet);
    }
#pragma unroll
    for (int q = 0; q < PPTL; ++q) {
        int p = tid + q * TOTT;
        int v = p >> 10, u = p & 1023;
        float uf = (float)u, vf = (float)v;
        float d0 = depth[p];
        float cx = (Ki[0] * uf + Ki[1] * vf + Ki[2]) * d0;
        float cy = (Ki[3] * uf + Ki[4] * vf + Ki[5]) * d0;
        float cz = (Ki[6] * uf + Ki[7] * vf + Ki[8]) * d0;
        int um = u > 0 ? u - 1 : 0, up = u < W_IMG - 1 ? u + 1 : W_IMG - 1;
        int vm = v > 0 ? v - 1 : 0, vp = v < H_IMG - 1 ? v + 1 : H_IMG - 1;
        float su = (u > 0 && u < W_IMG - 1) ? 0.5f : 1.0f;
        float sv = (v > 0 && v < H_IMG - 1) ? 0.5f : 1.0f;
        float dl = depth[v * W_IMG + um], dr = depth[v * W_IMG + up];
        float dt = depth[vm * W_IMG + u], db = depth[vp * W_IMG + u];
        float umf = (float)um, upf = (float)up, vmf = (float)vm, vpf = (float)vp;
        float lx = (Ki[0] * umf + Ki[1] * vf + Ki[2]) * dl;
        float ly = (Ki[3] * umf + Ki[4] * vf + Ki[5]) * dl;
        float lz = (Ki[6] * umf + Ki[7] * vf + Ki[8]) * dl;
        float rx = (Ki[0] * upf + Ki[1] * vf + Ki[2]) * dr;
        float ry = (Ki[3] * upf + Ki[4] * vf + Ki[5]) * dr;
        float rz = (Ki[6] * upf + Ki[7] * vf + Ki[8]) * dr;
        float tx = (Ki[0] * uf + Ki[1] * vmf + Ki[2]) * dt;
        float ty = (Ki[3] * uf + Ki[4] * vmf + Ki[5]) * dt;
        float tz = (Ki[6] * uf + Ki[7] * vmf + Ki[8]) * dt;
        float bx = (Ki[0] * uf + Ki[1] * vpf + Ki[2]) * db;
        float by = (Ki[3] * uf + Ki[4] * vpf + Ki[5]) * db;
        float bz = (Ki[6] * uf + Ki[7] * vpf + Ki[8]) * db;
        float dux = (rx - lx) * su, duy = (ry - ly) * su, duz = (rz - lz) * su;
        float dvx = (bx - tx) * sv, dvy = (by - ty) * sv, dvz = (bz - tz) * sv;
        float nx = duy * dvz - duz * dvy;
        float ny = duz * dvx - dux * dvz;
        float nz = dux * dvy - duy * dvx;
        float il = 1.0f / sqrtf(nx * nx + ny * ny + nz * nz + 1e-12f);
        nx *= il; ny *= il; nz *= il;
        if (PACKED) {
            float4 A = make_float4(cx, cy, cz, nx);
            float4 B = make_float4(ny, nz, 0.f, 0.f);
            reinterpret_cast<float4*>(refP)[2 * p]     = A;
            reinterpret_cast<float4*>(refP)[2 * p + 1] = B;
        } else {
            refG[3 * p + 0] = cx; refG[3 * p + 1] = cy; refG[3 * p + 2] = cz;
            refN[3 * p + 0] = nx; refN[3 * p + 1] = ny; refN[3 * p + 2] = nz;
        }
    }
}

// ---------------------------------------------------------------- sweep: residuals + block reduce -> partials[29][NB] col-major
template<int NB, bool PACKED>
__device__ __forceinline__ void dev_sweep(int it,
                                          const float* __restrict__ tp,
                                          const float* __restrict__ tn,
                                          const float* __restrict__ refP,
                                          const float* __restrict__ refG,
                                          const float* __restrict__ refN,
                                          const float* __restrict__ K,
                                          const float* __restrict__ poseG,
                                          float* __restrict__ partials,
                                          SharedScratch* sh) {
    constexpr int TOTT = NB * NTHR;
    constexpr int PPTL = NPTS / TOTT;
    const int tid = blockIdx.x * NTHR + threadIdx.x;

    if (threadIdx.x < 12) {
        sh->pose[threadIdx.x] = (it == 0)
            ? ((threadIdx.x == 0 || threadIdx.x == 4 || threadIdx.x == 8) ? 1.f : 0.f)
            : poseG[threadIdx.x];
    }
    __syncthreads();

    const float R0 = sh->pose[0], R1 = sh->pose[1], R2 = sh->pose[2];
    const float R3 = sh->pose[3], R4 = sh->pose[4], R5 = sh->pose[5];
    const float R6 = sh->pose[6], R7 = sh->pose[7], R8 = sh->pose[8];
    const float t0 = sh->pose[9], t1 = sh->pose[10], t2 = sh->pose[11];
    const float K0 = K[0], K1 = K[1], K2 = K[2];
    const float K3 = K[3], K4 = K[4], K5 = K[5];
    const float K6 = K[6], K7 = K[7], K8 = K[8];

    float acc[29];
#pragma unroll
    for (int k = 0; k < 29; ++k) acc[k] = 0.f;

#pragma unroll
    for (int q = 0; q < PPTL; ++q) {
        int i = tid + q * TOTT;
        float p0 = tp[3 * i + 0], p1 = tp[3 * i + 1], p2 = tp[3 * i + 2];
        float n0 = tn[3 * i + 0], n1 = tn[3 * i + 1], n2 = tn[3 * i + 2];
        float d0 = p0 - t0, d1 = p1 - t1, d2 = p2 - t2;
        float pc0 = R0 * d0 + R3 * d1 + R6 * d2;
        float pc1 = R1 * d0 + R4 * d1 + R7 * d2;
        float pc2 = R2 * d0 + R5 * d1 + R8 * d2;
        float nc0 = R0 * n0 + R3 * n1 + R6 * n2;
        float nc1 = R1 * n0 + R4 * n1 + R7 * n2;
        float nc2 = R2 * n0 + R5 * n1 + R8 * n2;
        float uu = K0 * pc0 + K1 * pc1 + K2 * pc2;
        float vv = K3 * pc0 + K4 * pc1 + K5 * pc2;
        float zz = K6 * pc0 + K7 * pc1 + K8 * pc2;
        float zs = (fabsf(zz) > 1e-8f) ? zz : 1e-8f;
        float uf = uu / zs, vf = vv / zs;
        bool valid = (uf > 0.f) && (uf < (float)W_IMG) && (vf > 0.f) && (vf < (float)H_IMG) && (zz > 1e-6f);
        int iu = (int)fminf(fmaxf(uf, 0.f), (float)(W_IMG - 1));
        int iv = (int)fminf(fmaxf(vf, 0.f), (float)(H_IMG - 1));
        int gidx = (iv << 10) + iu;
        float rg0, rg1, rg2, rn0, rn1, rn2;
        if (PACKED) {
            float4 A = reinterpret_cast<const float4*>(refP)[2 * gidx];
            float4 B = reinterpret_cast<const float4*>(refP)[2 * gidx + 1];
            rg0 = A.x; rg1 = A.y; rg2 = A.z; rn0 = A.w; rn1 = B.x; rn2 = B.y;
        } else {
            int gi = gidx * 3;
            rg0 = refG[gi + 0]; rg1 = refG[gi + 1]; rg2 = refG[gi + 2];
            rn0 = refN[gi + 0]; rn1 = refN[gi + 1]; rn2 = refN[gi + 2];
        }
        float dd0 = rg0 - pc0, dd1 = rg1 - pc1, dd2 = rg2 - pc2;
        float dist = sqrtf(dd0 * dd0 + dd1 * dd1 + dd2 * dd2 + 1e-12f);
        valid = valid && (dist < DIST_THR) && (rn0 * nc0 + rn1 * nc1 + rn2 * nc2 > NORMAL_THR);
        if (valid) {
            float rw0 = R0 * rg0 + R1 * rg1 + R2 * rg2 + t0;
            float rw1 = R3 * rg0 + R4 * rg1 + R5 * rg2 + t1;
            float rw2 = R6 * rg0 + R7 * rg1 + R8 * rg2 + t2;
            float r = n0 * (rw0 - p0) + n1 * (rw1 - p1) + n2 * (rw2 - p2);
            float J[6];
            J[0] = rw1 * n2 - rw2 * n1;
            J[1] = rw2 * n0 - rw0 * n2;
            J[2] = rw0 * n1 - rw1 * n0;
            J[3] = n0; J[4] = n1; J[5] = n2;
            int cI = 0;
#pragma unroll
            for (int a = 0; a < 6; ++a)
#pragma unroll
                for (int b = a; b < 6; ++b) acc[cI++] += J[a] * J[b];
#pragma unroll
            for (int a = 0; a < 6; ++a) acc[21 + a] += J[a] * r;
            acc[27] += r * r;
            acc[28] += 1.f;
        }
    }

#pragma unroll
    for (int k = 0; k < 29; ++k) {
#pragma unroll
        for (int off = 32; off > 0; off >>= 1) acc[k] += __shfl_down(acc[k], off);
    }
    int lane = threadIdx.x & 63, wv = threadIdx.x >> 6;
    if (lane == 0) {
#pragma unroll
        for (int k = 0; k < 29; ++k) sh->smemF[wv][k] = acc[k];
    }
    __syncthreads();
    if (threadIdx.x < 29) {
        partials[threadIdx.x * NB + blockIdx.x] =
            sh->smemF[0][threadIdx.x] + sh->smemF[1][threadIdx.x] +
            sh->smemF[2][threadIdx.x] + sh->smemF[3][threadIdx.x];
    }
}

// ---------------------------------------------------------------- stage-2 reduce + 7-lane parallel 6x7 solve (one block)
template<int NB>
__device__ __forceinline__ void dev_solve(const float* __restrict__ partials,
                                          double* __restrict__ xbuf,
                                          float* __restrict__ poseG,
                                          float* __restrict__ out, int last,
                                          SharedScratch* sh) {
    const int lane = threadIdx.x & 63, wv = threadIdx.x >> 6;
    // stage-2: wave w handles accumulators k = w, w+4, ... (2 live doubles max)
    for (int k = wv; k < 29; k += 4) {
        double s = 0.0;
#pragma unroll
        for (int j = 0; j < NB / 64; ++j)
            s += (double)partials[k * NB + lane + 64 * j];    // coalesced
#pragma unroll
        for (int off = 32; off > 0; off >>= 1) s += __shfl_down(s, off);
        if (lane == 0) sh->Tsh[k] = s;
    }
    __syncthreads();

    if (wv == 0) {
        // augmented system: lane j<6 holds column j of JtJ (+damping), lane>=6 holds rhs Jtr
        const int jj = (lane < 7) ? lane : 6;
        double col[6];
#pragma unroll
        for (int r = 0; r < 6; ++r) {
            if (jj == 6) col[r] = sh->Tsh[21 + r];
            else {
                int a = r < jj ? r : jj, b = r < jj ? jj : r;
                col[r] = sh->Tsh[ut_off(a, b)] + ((r == jj) ? 1e-9 : 0.0);
            }
        }
        // pivot-free elimination (SPD + damping), lanes = columns
#pragma unroll
        for (int c = 0; c < 6; ++c) {
            double diag = __shfl(col[c], c);
#pragma unroll
            for (int r = c + 1; r < 6; ++r) {
                double f = __shfl(col[r], c) / diag;
                col[r] -= f * col[c];
            }
        }
        // back-substitution (uniform across lanes via shuffles)
        double y[6];
#pragma unroll
        for (int i = 5; i >= 0; --i) {
            double s = __shfl(col[i], 6);
#pragma unroll
            for (int j2 = i + 1; j2 < 6; ++j2) s -= __shfl(col[i], j2) * y[j2];
            y[i] = s / __shfl(col[i], i);
        }
        if (lane == 0) {
            double x0 = xbuf[0] - y[0], x1 = xbuf[1] - y[1], x2 = xbuf[2] - y[2];
            double x3 = xbuf[3] - y[3], x4 = xbuf[4] - y[4], x5 = xbuf[5] - y[5];
            xbuf[0] = x0; xbuf[1] = x1; xbuf[2] = x2;
            xbuf[3] = x3; xbuf[4] = x4; xbuf[5] = x5;
            double th2 = x0 * x0 + x1 * x1 + x2 * x2;
            double th = sqrt(th2 + 1e-12);
            double sA = sin(th) / th;
            double sB = (1.0 - cos(th)) / (th2 + 1e-12);
            float r0 = (float)(1.0 + sB * (-(x1 * x1 + x2 * x2)));
            float r1 = (float)(sA * (-x2) + sB * (x0 * x1));
            float r2 = (float)(sA * ( x1) + sB * (x0 * x2));
            float r3 = (float)(sA * ( x2) + sB * (x0 * x1));
            float r4 = (float)(1.0 + sB * (-(x0 * x0 + x2 * x2)));
            float r5 = (float)(sA * (-x0) + sB * (x1 * x2));
            float r6 = (float)(sA * (-x1) + sB * (x0 * x2));
            float r7 = (float)(sA * ( x0) + sB * (x1 * x2));
            float r8 = (float)(1.0 + sB * (-(x0 * x0 + x1 * x1)));
            poseG[0] = r0; poseG[1] = r1; poseG[2] = r2;
            poseG[3] = r3; poseG[4] = r4; poseG[5] = r5;
            poseG[6] = r6; poseG[7] = r7; poseG[8] = r8;
            poseG[9] = (float)x3; poseG[10] = (float)x4; poseG[11] = (float)x5;
            if (last) {
                double cost = sh->Tsh[27] / fmax(sh->Tsh[28], 1.0);
                out[0]  = r0; out[1]  = r1; out[2]  = r2; out[3]  = (float)x3;
                out[4]  = r3; out[5]  = r4; out[6]  = r5; out[7]  = (float)x4;
                out[8]  = r6; out[9]  = r7; out[10] = r8; out[11] = (float)x5;
                out[12] = 0.f; out[13] = 0.f; out[14] = 0.f; out[15] = 1.f;
                out[16] = (float)cost;
            }
        }
    }
}

// ---------------------------------------------------------------- cooperative single-kernel
template<int NB, bool PACKED>
__global__ __launch_bounds__(NTHR, NB / 256) void icp_coop(
    const float* __restrict__ depth, const float* __restrict__ tp,
    const float* __restrict__ tn, const float* __restrict__ K,
    float* __restrict__ out, float* __restrict__ refP,
    float* __restrict__ refG, float* __restrict__ refN,
    float* __restrict__ partials, float* __restrict__ poseG,
    double* __restrict__ xbuf) {
    constexpr int TOTT = NB * NTHR;
    constexpr int PPTL = NPTS / TOTT;
    __shared__ SharedScratch sh;
    cg::grid_group gg = cg::this_grid();
    const int tid = blockIdx.x * NTHR + threadIdx.x;

    dev_prep<PPTL, TOTT, PACKED>(tid, depth, K, refP, refG, refN);
    if (blockIdx.x == 0 && threadIdx.x == 0) {
#pragma unroll
        for (int k = 0; k < 6; ++k) xbuf[k] = 0.0;
    }
    gg.sync();

    for (int it = 0; it < NITER; ++it) {
        dev_sweep<NB, PACKED>(it, tp, tn, refP, refG, refN, K, poseG, partials, &sh);
        gg.sync();                       // partials complete
        if (blockIdx.x == 0)
            dev_solve<NB>(partials, xbuf, poseG, out, it == NITER - 1 ? 1 : 0, &sh);
        gg.sync();                       // pose visible
    }
}

// ---------------------------------------------------------------- multi-dispatch fallback (256 blocks)
template<bool PACKED>
__global__ __launch_bounds__(NTHR) void k_prep_f(const float* __restrict__ depth,
                                                 const float* __restrict__ K,
                                                 float* __restrict__ refP,
                                                 float* __restrict__ refG,
                                                 float* __restrict__ refN,
                                                 double* __restrict__ xbuf) {
    dev_prep<12, 65536, PACKED>(blockIdx.x * NTHR + threadIdx.x, depth, K, refP, refG, refN);
    if (blockIdx.x == 0 && threadIdx.x == 0) {
#pragma unroll
        for (int k = 0; k < 6; ++k) xbuf[k] = 0.0;
    }
}

template<bool PACKED>
__global__ __launch_bounds__(NTHR) void k_sweep_f(int it,
                                                  const float* __restrict__ tp,
                                                  const float* __restrict__ tn,
                                                  const float* __restrict__ refP,
                                                  const float* __restrict__ refG,
                                                  const float* __restrict__ refN,
                                                  const float* __restrict__ K,
                                                  const float* __restrict__ poseG,
                                                  float* __restrict__ partials) {
    __shared__ SharedScratch sh;
    dev_sweep<256, PACKED>(it, tp, tn, refP, refG, refN, K, poseG, partials, &sh);
}

__global__ __launch_bounds__(NTHR) void k_solve_f(int it, const float* __restrict__ partials,
                                                  double* __restrict__ xbuf,
                                                  float* __restrict__ poseG,
                                                  float* __restrict__ out) {
    __shared__ SharedScratch sh;
    dev_solve<256>(partials, xbuf, poseG, out, it == NITER - 1 ? 1 : 0, &sh);
}

// ---------------------------------------------------------------- launch
extern "C" void kernel_launch(void* const* d_in, const int* in_sizes, int n_in,
                              void* d_out, int out_size, void* d_ws, size_t ws_size,
                              hipStream_t stream) {
    const float* ref_depth      = (const float*)d_in[0];
    const float* target_pts     = (const float*)d_in[1];
    const float* target_normals = (const float*)d_in[2];
    const float* K              = (const float*)d_in[3];
    float* out = (float*)d_out;
    char* ws = (char*)d_ws;

    const size_t packed_bytes   = (size_t)NPTS * 8 * sizeof(float);   // 25,165,824
    const size_t unpacked_bytes = (size_t)NPTS * 6 * sizeof(float);   // 18,874,368
    const size_t tail_bytes     = (size_t)32 * 1024 * sizeof(float) + 256;
    const bool packed = ws_size >= packed_bytes + tail_bytes;

    float*  refP     = (float*)ws;
    float*  refG     = (float*)ws;
    float*  refN     = (float*)(ws + (size_t)NPTS * 3 * sizeof(float));
    float*  partials = (float*)(ws + (packed ? packed_bytes : unpacked_bytes));
    float*  poseG    = partials + 32 * 1024;
    double* xbuf     = (double*)(poseG + 16);

    void* args[] = {
        (void*)&ref_depth, (void*)&target_pts, (void*)&target_normals, (void*)&K,
        (void*)&out, (void*)&refP, (void*)&refG, (void*)&refN,
        (void*)&partials, (void*)&poseG, (void*)&xbuf
    };

    const void* f1024 = packed ? (const void*)&icp_coop<1024, true> : (const void*)&icp_coop<1024, false>;
    const void* f512  = packed ? (const void*)&icp_coop<512,  true> : (const void*)&icp_coop<512,  false>;

    hipError_t err = hipLaunchCooperativeKernel(f1024, dim3(1024), dim3(NTHR), args, 0, stream);
    if (err != hipSuccess)
        err = hipLaunchCooperativeKernel(f512, dim3(512), dim3(NTHR), args, 0, stream);
    if (err != hipSuccess) {
        // last-resort multi-dispatch pipeline (kernel boundaries = device-wide sync)
        if (packed)
            k_prep_f<true><<<256, NTHR, 0, stream>>>(ref_depth, K, refP, refG, refN, xbuf);
        else
            k_prep_f<false><<<256, NTHR, 0, stream>>>(ref_depth, K, refP, refG, refN, xbuf);
        for (int it = 0; it < NITER; ++it) {
            if (packed)
                k_sweep_f<true><<<256, NTHR, 0, stream>>>(it, target_pts, target_normals,
                                                          refP, refG, refN, K, poseG, partials);
            else
                k_sweep_f<false><<<256, NTHR, 0, stream>>>(it, target_pts, target_normals,
                                                           refP, refG, refN, K, poseG, partials);
            k_solve_f<<<1, NTHR, 0, stream>>>(it, partials, xbuf, poseG, out);
        }
    }
}